// Round 1
// baseline (642.434 us; speedup 1.0000x reference)
//
#include <hip/hip_runtime.h>

#define DEV static __device__ __forceinline__

typedef unsigned short u16;
typedef short bf16x8 __attribute__((ext_vector_type(8)));
typedef u16 u16x8v __attribute__((ext_vector_type(8)));
typedef u16 u16x4v __attribute__((ext_vector_type(4)));
typedef float f32x4 __attribute__((ext_vector_type(4)));

static constexpr int NB = 4, L = 1024, D = 512, H = 8, DH = 64;
static constexpr size_t E  = (size_t)NB * L * D;   // 2,097,152 elems per [4,1024,512]
static constexpr size_t WE = (size_t)D * D;        // 262,144 elems per weight

// d_ws layout in u16 units (total 14E + 12WE = 32,505,856 u16 = ~62 MB)
static constexpr size_t OFF_X1H = 0;
static constexpr size_t OFF_X1L = OFF_X1H + E;
static constexpr size_t OFF_X2H = OFF_X1L + E;
static constexpr size_t OFF_X2L = OFF_X2H + E;
static constexpr size_t OFF_WH  = OFF_X2L + E;       // 6 x WE (hi)
static constexpr size_t OFF_WL  = OFF_WH + 6 * WE;   // 6 x WE (lo)
static constexpr size_t OFF_QKV = OFF_WL + 6 * WE;
// OFF_QKV + {0:q1h, 1E:q1l, 2E:k1h, 3E:k1l, 4E:q2h, 5E:q2l, 6E:k2h, 7E:k2l, 8E:v1t, 9E:v2t}

DEV u16 f2bf(float x) {
    unsigned u = __builtin_bit_cast(unsigned, x);
    unsigned r = u + 0x7FFFu + ((u >> 16) & 1u);
    return (u16)(r >> 16);
}
DEV float bf2f(u16 h) {
    unsigned u = ((unsigned)h) << 16;
    return __builtin_bit_cast(float, u);
}
DEV bf16x8 ldfrag(const u16* p) {
    u16x8v t = *reinterpret_cast<const u16x8v*>(p);
    return __builtin_bit_cast(bf16x8, t);
}

// ---------------- split fp32 -> (hi, lo) bf16 ----------------
__global__ __launch_bounds__(256) void k_split(const float* __restrict__ in,
                                               u16* __restrict__ hi, u16* __restrict__ lo,
                                               int n4) {
    int i = blockIdx.x * 256 + threadIdx.x;
    if (i >= n4) return;
    float4 v = reinterpret_cast<const float4*>(in)[i];
    float xs[4] = {v.x, v.y, v.z, v.w};
    u16x4v h, l;
#pragma unroll
    for (int j = 0; j < 4; j++) {
        u16 hh = f2bf(xs[j]);
        h[j] = hh;
        l[j] = f2bf(xs[j] - bf2f(hh));
    }
    reinterpret_cast<u16x4v*>(hi)[i] = h;
    reinterpret_cast<u16x4v*>(lo)[i] = l;
}

// ---------------- projections: C[l,d] = sum_e X[l,e] * W[d,e] (split bf16, 3 MFMA terms) ----------------
// grid: 6 projections x 64 mtiles x 8 ntiles = 3072 blocks of 256 threads
__global__ __launch_bounds__(256) void k_proj(u16* __restrict__ ws) {
    const int b     = blockIdx.x;
    const int proj  = b >> 9;        // 0..5 : q1,k1,v1,q2,k2,v2
    const int rem   = b & 511;
    const int mtile = rem >> 3;      // 64 tiles of 64 rows over M=4096
    const int ntile = rem & 7;       // 8 tiles of 64 cols over N=512
    const int tid   = threadIdx.x;
    const int w     = tid >> 6;
    const int lane  = tid & 63;
    const int lr    = lane & 15;
    const int g     = lane >> 4;

    const int src  = proj / 3;       // 0 -> X1, 1 -> X2
    const int kind = proj % 3;       // 0=q, 1=k, 2=v
    const u16* Xh = ws + (src ? OFF_X2H : OFF_X1H);
    const u16* Xl = ws + (src ? OFF_X2L : OFF_X1L);
    const u16* Wh = ws + OFF_WH + (size_t)proj * WE;
    const u16* Wl = ws + OFF_WL + (size_t)proj * WE;

    const int m0 = mtile * 64 + w * 16;  // this wave's 16 rows
    const int n0 = ntile * 64;

    f32x4 acc[4] = {{0,0,0,0},{0,0,0,0},{0,0,0,0},{0,0,0,0}};
    const u16* xrh = Xh + (size_t)(m0 + lr) * D + g * 8;
    const u16* xrl = Xl + (size_t)(m0 + lr) * D + g * 8;
#pragma unroll 4
    for (int e = 0; e < D; e += 32) {
        bf16x8 ah = ldfrag(xrh + e);
        bf16x8 al = ldfrag(xrl + e);
#pragma unroll
        for (int cb = 0; cb < 4; cb++) {
            const u16* pwh = Wh + (size_t)(n0 + cb * 16 + lr) * D + e + g * 8;
            const u16* pwl = Wl + (size_t)(n0 + cb * 16 + lr) * D + e + g * 8;
            bf16x8 bh = ldfrag(pwh);
            bf16x8 bl = ldfrag(pwl);
            acc[cb] = __builtin_amdgcn_mfma_f32_16x16x32_bf16(ah, bh, acc[cb], 0, 0, 0);
            acc[cb] = __builtin_amdgcn_mfma_f32_16x16x32_bf16(ah, bl, acc[cb], 0, 0, 0);
            acc[cb] = __builtin_amdgcn_mfma_f32_16x16x32_bf16(al, bh, acc[cb], 0, 0, 0);
        }
    }

    // epilogue: C layout col = lane&15, row = g*4 + r  [m89]
    if (kind < 2) {
        u16* dhi = ws + OFF_QKV + (size_t)(src * 4 + kind * 2) * E;
        u16* dlo = dhi + E;
#pragma unroll
        for (int cb = 0; cb < 4; cb++) {
            int d  = n0 + cb * 16 + lr;
            int hh = d >> 6, dh = d & 63;
#pragma unroll
            for (int r = 0; r < 4; r++) {
                int m = m0 + g * 4 + r;
                int n = m >> 10, li = m & 1023;
                size_t idx = ((size_t)(n * H + hh) * L + li) * DH + dh;
                float v = acc[cb][r];
                u16 hv = f2bf(v);
                dhi[idx] = hv;
                dlo[idx] = f2bf(v - bf2f(hv));
            }
        }
    } else {
        u16* vt = ws + OFF_QKV + (size_t)(8 + src) * E;
#pragma unroll
        for (int cb = 0; cb < 4; cb++) {
            int d  = n0 + cb * 16 + lr;
            int hh = d >> 6, dh = d & 63;
            int m  = m0 + g * 4;
            int n  = m >> 10, li = m & 1023;
            u16x4v pk;
#pragma unroll
            for (int r = 0; r < 4; r++) pk[r] = f2bf(acc[cb][r]);
            *reinterpret_cast<u16x4v*>(vt + ((size_t)(n * H + hh) * DH + dh) * L + li) = pk;
        }
    }
}

// ---------------- fused two-source flash attention ----------------
// grid: 2 outputs x 4 n x 8 h x 16 qtiles = 1024 blocks of 256 threads
__global__ __launch_bounds__(256) void k_attn(const u16* __restrict__ ws,
                                              const float* __restrict__ mask1,
                                              const float* __restrict__ mask2,
                                              float* __restrict__ out) {
    __shared__ __align__(16) u16 plds[4][16][64];  // per-wave P tile, XOR-swizzled

    const int b    = blockIdx.x;
    const int oi   = b >> 9;
    const int rem  = b & 511;
    const int qt   = rem & 15;
    const int hh   = (rem >> 4) & 7;
    const int n    = rem >> 7;
    const int tid  = threadIdx.x;
    const int w    = tid >> 6;
    const int lane = tid & 63;
    const int lr   = lane & 15;
    const int g    = lane >> 4;

    const u16* Qh = ws + OFF_QKV + (size_t)(oi * 4) * E;
    const u16* Ql = Qh + E;
    const float* maskrow = oi ? mask2 : mask1;

    const int l0 = qt * 64 + w * 16;
    const size_t qbase = ((size_t)(n * H + hh) * L + l0 + lr) * DH + g * 8;
    bf16x8 qh0 = ldfrag(Qh + qbase), qh1 = ldfrag(Qh + qbase + 32);
    bf16x8 ql0 = ldfrag(Ql + qbase), ql1 = ldfrag(Ql + qbase + 32);

    float ofin[4][4];  // [d][r] finalized source-A (then averaged) output

#pragma unroll 1
    for (int s = 0; s < 2; s++) {
        const u16* Kh = ws + OFF_QKV + (size_t)(2 + s * 4) * E;
        const u16* Kl = Kh + E;
        const u16* Vt = ws + OFF_QKV + (size_t)(8 + s) * E;
        const float* maskc = s ? mask2 : mask1;

        float mrun[4], lrun[4];
        f32x4 oacc[4];
#pragma unroll
        for (int r = 0; r < 4; r++) { mrun[r] = -1e30f; lrun[r] = 0.f; }
#pragma unroll
        for (int d = 0; d < 4; d++) oacc[d] = {0.f, 0.f, 0.f, 0.f};

#pragma unroll 1
        for (int kt = 0; kt < 16; kt++) {
            f32x4 sfr[4];
#pragma unroll
            for (int j = 0; j < 4; j++) {
                const int key = kt * 64 + j * 16;
                const size_t kb = ((size_t)(n * H + hh) * L + key + lr) * DH + g * 8;
                bf16x8 kh0 = ldfrag(Kh + kb), kh1 = ldfrag(Kh + kb + 32);
                bf16x8 kl0 = ldfrag(Kl + kb), kl1 = ldfrag(Kl + kb + 32);
                f32x4 a = {0.f, 0.f, 0.f, 0.f};
                a = __builtin_amdgcn_mfma_f32_16x16x32_bf16(qh0, kh0, a, 0, 0, 0);
                a = __builtin_amdgcn_mfma_f32_16x16x32_bf16(qh1, kh1, a, 0, 0, 0);
                a = __builtin_amdgcn_mfma_f32_16x16x32_bf16(qh0, kl0, a, 0, 0, 0);
                a = __builtin_amdgcn_mfma_f32_16x16x32_bf16(qh1, kl1, a, 0, 0, 0);
                a = __builtin_amdgcn_mfma_f32_16x16x32_bf16(ql0, kh0, a, 0, 0, 0);
                a = __builtin_amdgcn_mfma_f32_16x16x32_bf16(ql1, kh1, a, 0, 0, 0);
                float mc = maskc[n * L + key + lr];
                if (mc <= 0.f) {
                    a[0] -= 10000.f; a[1] -= 10000.f; a[2] -= 10000.f; a[3] -= 10000.f;
                }
                sfr[j] = a;
            }
            // online softmax per row r (rows replicated across the 16 lanes of each g-group)
            float pv[4][4];
#pragma unroll
            for (int r = 0; r < 4; r++) {
                float tm = fmaxf(fmaxf(sfr[0][r], sfr[1][r]), fmaxf(sfr[2][r], sfr[3][r]));
#pragma unroll
                for (int mk = 1; mk < 16; mk <<= 1) tm = fmaxf(tm, __shfl_xor(tm, mk, 64));
                float mnew = fmaxf(mrun[r], tm);
                float sc = expf(mrun[r] - mnew);
                float ps = 0.f;
#pragma unroll
                for (int j = 0; j < 4; j++) {
                    float p = expf(sfr[j][r] - mnew);
                    pv[j][r] = p;
                    ps += p;
                }
#pragma unroll
                for (int mk = 1; mk < 16; mk <<= 1) ps += __shfl_xor(ps, mk, 64);
                mrun[r] = mnew;
                lrun[r] = lrun[r] * sc + ps;
#pragma unroll
                for (int d = 0; d < 4; d++) oacc[d][r] *= sc;
            }
            // P -> bf16 -> swizzled LDS (per-wave private; compiler orders ds ops)
#pragma unroll
            for (int j = 0; j < 4; j++)
#pragma unroll
                for (int r = 0; r < 4; r++) {
                    int row = g * 4 + r;
                    int key = j * 16 + lr;
                    plds[w][row][key ^ ((row & 7) << 3)] = f2bf(pv[j][r]);
                }
            // read P as A-fragments (row = lr, 8 consecutive keys per lane)
            bf16x8 pa[2];
#pragma unroll
            for (int ks = 0; ks < 2; ks++) {
                int base = (ks * 32 + g * 8) ^ ((lr & 7) << 3);
                u16x8v t = *reinterpret_cast<const u16x8v*>(&plds[w][lr][base]);
                pa[ks] = __builtin_bit_cast(bf16x8, t);
            }
            // O += P * V   (V^T stored [n][h][dh][l] so B-frags are contiguous)
#pragma unroll
            for (int d = 0; d < 4; d++) {
#pragma unroll
                for (int ks = 0; ks < 2; ks++) {
                    const size_t vb = ((size_t)(n * H + hh) * DH + d * 16 + lr) * L
                                      + kt * 64 + ks * 32 + g * 8;
                    bf16x8 v8 = ldfrag(Vt + vb);
                    oacc[d] = __builtin_amdgcn_mfma_f32_16x16x32_bf16(pa[ks], v8, oacc[d], 0, 0, 0);
                }
            }
        }
        if (s == 0) {
#pragma unroll
            for (int d = 0; d < 4; d++)
#pragma unroll
                for (int r = 0; r < 4; r++) ofin[d][r] = oacc[d][r] / lrun[r];
        } else {
#pragma unroll
            for (int d = 0; d < 4; d++)
#pragma unroll
                for (int r = 0; r < 4; r++) ofin[d][r] = 0.5f * (ofin[d][r] + oacc[d][r] / lrun[r]);
        }
    }

    float* ob = out + (size_t)oi * ((size_t)NB * L * D);
#pragma unroll
    for (int r = 0; r < 4; r++) {
        int row = l0 + g * 4 + r;
        float mr = maskrow[n * L + row];
#pragma unroll
        for (int d = 0; d < 4; d++) {
            float v = (mr > 0.f) ? ofin[d][r] : 0.f;
            ob[((size_t)n * L + row) * D + hh * DH + d * 16 + lr] = v;
        }
    }
}

extern "C" void kernel_launch(void* const* d_in, const int* in_sizes, int n_in,
                              void* d_out, int out_size, void* d_ws, size_t ws_size,
                              hipStream_t stream) {
    const float* input1 = (const float*)d_in[0];
    const float* mask1  = (const float*)d_in[1];
    const float* input2 = (const float*)d_in[2];
    const float* mask2  = (const float*)d_in[3];
    const float* Wm[6]  = {(const float*)d_in[4], (const float*)d_in[5], (const float*)d_in[6],
                           (const float*)d_in[7], (const float*)d_in[8], (const float*)d_in[9]};
    u16*   ws  = (u16*)d_ws;
    float* out = (float*)d_out;

    // split X1, X2
    k_split<<<(int)(E / 4 / 256), 256, 0, stream>>>(input1, ws + OFF_X1H, ws + OFF_X1L, (int)(E / 4));
    k_split<<<(int)(E / 4 / 256), 256, 0, stream>>>(input2, ws + OFF_X2H, ws + OFF_X2L, (int)(E / 4));
    // split weights
    for (int i = 0; i < 6; i++)
        k_split<<<(int)(WE / 4 / 256), 256, 0, stream>>>(Wm[i], ws + OFF_WH + (size_t)i * WE,
                                                         ws + OFF_WL + (size_t)i * WE, (int)(WE / 4));
    // projections
    k_proj<<<3072, 256, 0, stream>>>(ws);
    // attention + average + mask + write
    k_attn<<<1024, 256, 0, stream>>>(ws, mask1, mask2, out);
}

// Round 2
// 553.167 us; speedup vs baseline: 1.1614x; 1.1614x over previous
//
#include <hip/hip_runtime.h>

#define DEV static __device__ __forceinline__

typedef unsigned short u16;
typedef short bf16x8 __attribute__((ext_vector_type(8)));
typedef u16 u16x8v __attribute__((ext_vector_type(8)));
typedef u16 u16x4v __attribute__((ext_vector_type(4)));
typedef float f32x4 __attribute__((ext_vector_type(4)));

static constexpr int NB = 4, L = 1024, D = 512, H = 8, DH = 64;
static constexpr size_t E  = (size_t)NB * L * D;   // 2,097,152
static constexpr size_t WE = (size_t)D * D;        // 262,144

// d_ws layout in u16 units
static constexpr size_t OFF_X1H = 0;
static constexpr size_t OFF_X1L = OFF_X1H + E;
static constexpr size_t OFF_X2H = OFF_X1L + E;
static constexpr size_t OFF_X2L = OFF_X2H + E;
static constexpr size_t OFF_WH  = OFF_X2L + E;       // 6 x WE
static constexpr size_t OFF_WL  = OFF_WH + 6 * WE;   // 6 x WE
static constexpr size_t OFF_QKV = OFF_WL + 6 * WE;
// OFF_QKV + {0:q1h,1E:q1l,2E:k1h,3E:k1l,4E:q2h,5E:q2l,6E:k2h,7E:k2l,8E:v1t,9E:v2t}
static constexpr size_t OFF_VLEN = OFF_QKV + 10 * E; // int[8] (s*4+n)

DEV u16 f2bf(float x) {
    unsigned u = __builtin_bit_cast(unsigned, x);
    unsigned r = u + 0x7FFFu + ((u >> 16) & 1u);
    return (u16)(r >> 16);
}
DEV float bf2f(u16 h) {
    unsigned u = ((unsigned)h) << 16;
    return __builtin_bit_cast(float, u);
}
DEV bf16x8 ldfrag(const u16* p) {
    u16x8v t = *reinterpret_cast<const u16x8v*>(p);
    return __builtin_bit_cast(bf16x8, t);
}

// ---------------- split fp32 -> (hi, lo) bf16 ----------------
__global__ __launch_bounds__(256) void k_split(const float* __restrict__ in,
                                               u16* __restrict__ hi, u16* __restrict__ lo,
                                               int n4) {
    int i = blockIdx.x * 256 + threadIdx.x;
    if (i >= n4) return;
    float4 v = reinterpret_cast<const float4*>(in)[i];
    float xs[4] = {v.x, v.y, v.z, v.w};
    u16x4v h, l;
#pragma unroll
    for (int j = 0; j < 4; j++) {
        u16 hh = f2bf(xs[j]);
        h[j] = hh;
        l[j] = f2bf(xs[j] - bf2f(hh));
    }
    reinterpret_cast<u16x4v*>(hi)[i] = h;
    reinterpret_cast<u16x4v*>(lo)[i] = l;
}

// ---------------- valid-length per (src, n): prefix-mask sum ----------------
__global__ __launch_bounds__(256) void k_vlen(const float* __restrict__ m1,
                                              const float* __restrict__ m2,
                                              int* __restrict__ vl) {
    int b = blockIdx.x;            // 0..7 : s*4+n
    int s = b >> 2, n = b & 3;
    const float* m = (s ? m2 : m1) + n * L;
    float p = 0.f;
    for (int i = threadIdx.x; i < L; i += 256) p += m[i];
#pragma unroll
    for (int mk = 1; mk < 64; mk <<= 1) p += __shfl_xor(p, mk, 64);
    __shared__ float w4[4];
    if ((threadIdx.x & 63) == 0) w4[threadIdx.x >> 6] = p;
    __syncthreads();
    if (threadIdx.x == 0) vl[b] = (int)(w4[0] + w4[1] + w4[2] + w4[3] + 0.5f);
}

// ---------------- projections, 128x64 block tile, 32 rows/wave ----------------
// grid: 6 x 32 mtiles x 8 ntiles = 1536 blocks of 256 threads
__global__ __launch_bounds__(256) void k_proj(u16* __restrict__ ws) {
    const int b     = blockIdx.x;
    const int proj  = b >> 8;        // 0..5 : q1,k1,v1,q2,k2,v2
    const int rem   = b & 255;
    const int mtile = rem >> 3;      // 32 tiles of 128 rows
    const int ntile = rem & 7;       // 8 tiles of 64 cols
    const int tid   = threadIdx.x;
    const int w     = tid >> 6;
    const int lane  = tid & 63;
    const int lr    = lane & 15;
    const int g     = lane >> 4;

    const int src  = proj / 3;
    const int kind = proj % 3;
    const u16* Xh = ws + (src ? OFF_X2H : OFF_X1H);
    const u16* Xl = ws + (src ? OFF_X2L : OFF_X1L);
    const u16* Wh = ws + OFF_WH + (size_t)proj * WE;
    const u16* Wl = ws + OFF_WL + (size_t)proj * WE;

    const int m0 = mtile * 128 + w * 32;   // this wave's 32 rows
    const int n0 = ntile * 64;

    f32x4 acc[2][4];
#pragma unroll
    for (int rb = 0; rb < 2; rb++)
#pragma unroll
        for (int cb = 0; cb < 4; cb++) acc[rb][cb] = {0.f, 0.f, 0.f, 0.f};

    const u16* xh0 = Xh + (size_t)(m0 + lr) * D + g * 8;
    const u16* xh1 = Xh + (size_t)(m0 + 16 + lr) * D + g * 8;
    const u16* xl0 = Xl + (size_t)(m0 + lr) * D + g * 8;
    const u16* xl1 = Xl + (size_t)(m0 + 16 + lr) * D + g * 8;
#pragma unroll 4
    for (int e = 0; e < D; e += 32) {
        bf16x8 ah0 = ldfrag(xh0 + e), ah1 = ldfrag(xh1 + e);
        bf16x8 al0 = ldfrag(xl0 + e), al1 = ldfrag(xl1 + e);
#pragma unroll
        for (int cb = 0; cb < 4; cb++) {
            const u16* pwh = Wh + (size_t)(n0 + cb * 16 + lr) * D + e + g * 8;
            const u16* pwl = Wl + (size_t)(n0 + cb * 16 + lr) * D + e + g * 8;
            bf16x8 bh = ldfrag(pwh);
            bf16x8 bl = ldfrag(pwl);
            acc[0][cb] = __builtin_amdgcn_mfma_f32_16x16x32_bf16(ah0, bh, acc[0][cb], 0, 0, 0);
            acc[0][cb] = __builtin_amdgcn_mfma_f32_16x16x32_bf16(ah0, bl, acc[0][cb], 0, 0, 0);
            acc[0][cb] = __builtin_amdgcn_mfma_f32_16x16x32_bf16(al0, bh, acc[0][cb], 0, 0, 0);
            acc[1][cb] = __builtin_amdgcn_mfma_f32_16x16x32_bf16(ah1, bh, acc[1][cb], 0, 0, 0);
            acc[1][cb] = __builtin_amdgcn_mfma_f32_16x16x32_bf16(ah1, bl, acc[1][cb], 0, 0, 0);
            acc[1][cb] = __builtin_amdgcn_mfma_f32_16x16x32_bf16(al1, bh, acc[1][cb], 0, 0, 0);
        }
    }

    if (kind < 2) {
        u16* dhi = ws + OFF_QKV + (size_t)(src * 4 + kind * 2) * E;
        u16* dlo = dhi + E;
#pragma unroll
        for (int rb = 0; rb < 2; rb++)
#pragma unroll
            for (int cb = 0; cb < 4; cb++) {
                int d  = n0 + cb * 16 + lr;
                int hh = d >> 6, dh = d & 63;
#pragma unroll
                for (int r = 0; r < 4; r++) {
                    int m = m0 + rb * 16 + g * 4 + r;
                    int n = m >> 10, li = m & 1023;
                    size_t idx = ((size_t)(n * H + hh) * L + li) * DH + dh;
                    float v = acc[rb][cb][r];
                    u16 hv = f2bf(v);
                    dhi[idx] = hv;
                    dlo[idx] = f2bf(v - bf2f(hv));
                }
            }
    } else {
        u16* vt = ws + OFF_QKV + (size_t)(8 + src) * E;
#pragma unroll
        for (int rb = 0; rb < 2; rb++)
#pragma unroll
            for (int cb = 0; cb < 4; cb++) {
                int d  = n0 + cb * 16 + lr;
                int hh = d >> 6, dh = d & 63;
                int m  = m0 + rb * 16 + g * 4;
                int n  = m >> 10, li = m & 1023;
                u16x4v pk;
#pragma unroll
                for (int r = 0; r < 4; r++) pk[r] = f2bf(acc[rb][cb][r]);
                *reinterpret_cast<u16x4v*>(vt + ((size_t)(n * H + hh) * DH + dh) * L + li) = pk;
            }
    }
}

// ---------------- fused two-source flash attention, 8 waves/block ----------------
// grid: 2 outputs x 4 n x 8 h x 16 qtiles = 1024 blocks of 512 threads.
// waves 0-3 handle key-source 0, waves 4-7 key-source 1; combine via LDS.
__global__ __launch_bounds__(512) void k_attn(const u16* __restrict__ ws,
                                              const float* __restrict__ mask1,
                                              const float* __restrict__ mask2,
                                              float* __restrict__ out) {
    __shared__ __align__(16) u16 plds[8][16][64];    // per-wave P tile, XOR-swizzled (16KB)
    __shared__ float comb[4][16][64];                // combine buffer (16KB)

    const int b    = blockIdx.x;
    const int oi   = b >> 9;
    const int rem  = b & 511;
    const int qt   = rem & 15;
    const int hh   = (rem >> 4) & 7;
    const int n    = rem >> 7;
    const int tid  = threadIdx.x;
    const int w    = tid >> 6;
    const int s    = w >> 2;        // key source
    const int wq   = w & 3;         // q sub-tile
    const int lane = tid & 63;
    const int lr   = lane & 15;
    const int g    = lane >> 4;

    const u16* Qh = ws + OFF_QKV + (size_t)(oi * 4) * E;
    const u16* Ql = Qh + E;
    const float* maskrow = oi ? mask2 : mask1;
    const float* maskc   = s  ? mask2 : mask1;
    const int* vl = (const int*)(ws + OFF_VLEN);

    const int l0 = qt * 64 + wq * 16;
    const size_t qbase = ((size_t)(n * H + hh) * L + l0 + lr) * DH + g * 8;
    bf16x8 qh0 = ldfrag(Qh + qbase), qh1 = ldfrag(Qh + qbase + 32);
    bf16x8 ql0 = ldfrag(Ql + qbase), ql1 = ldfrag(Ql + qbase + 32);

    const u16* Kh = ws + OFF_QKV + (size_t)(2 + s * 4) * E;
    const u16* Kl = Kh + E;
    const u16* Vt = ws + OFF_QKV + (size_t)(8 + s) * E;

    float mrun[4], lrun[4];
    f32x4 oacc[4];
#pragma unroll
    for (int r = 0; r < 4; r++) { mrun[r] = -1e30f; lrun[r] = 0.f; }
#pragma unroll
    for (int d = 0; d < 4; d++) oacc[d] = {0.f, 0.f, 0.f, 0.f};

    const int nkt = (vl[s * 4 + n] + 63) >> 6;

#pragma unroll 1
    for (int kt = 0; kt < nkt; kt++) {
        f32x4 sfr[4];
#pragma unroll
        for (int j = 0; j < 4; j++) {
            const int key = kt * 64 + j * 16;
            const size_t kb = ((size_t)(n * H + hh) * L + key + lr) * DH + g * 8;
            bf16x8 kh0 = ldfrag(Kh + kb), kh1 = ldfrag(Kh + kb + 32);
            bf16x8 kl0 = ldfrag(Kl + kb), kl1 = ldfrag(Kl + kb + 32);
            f32x4 a = {0.f, 0.f, 0.f, 0.f};
            a = __builtin_amdgcn_mfma_f32_16x16x32_bf16(qh0, kh0, a, 0, 0, 0);
            a = __builtin_amdgcn_mfma_f32_16x16x32_bf16(qh1, kh1, a, 0, 0, 0);
            a = __builtin_amdgcn_mfma_f32_16x16x32_bf16(qh0, kl0, a, 0, 0, 0);
            a = __builtin_amdgcn_mfma_f32_16x16x32_bf16(qh1, kl1, a, 0, 0, 0);
            a = __builtin_amdgcn_mfma_f32_16x16x32_bf16(ql0, kh0, a, 0, 0, 0);
            a = __builtin_amdgcn_mfma_f32_16x16x32_bf16(ql1, kh1, a, 0, 0, 0);
            float sub = (maskc[n * L + key + lr] > 0.f) ? 0.f : 10000.f;
            a[0] -= sub; a[1] -= sub; a[2] -= sub; a[3] -= sub;
            sfr[j] = a;
        }
        // online softmax per row r (row replicated across the 16 lr-lanes of each g-group)
#pragma unroll
        for (int r = 0; r < 4; r++) {
            float tm = fmaxf(fmaxf(sfr[0][r], sfr[1][r]), fmaxf(sfr[2][r], sfr[3][r]));
#pragma unroll
            for (int mk = 1; mk < 16; mk <<= 1) tm = fmaxf(tm, __shfl_xor(tm, mk, 64));
            float mnew = fmaxf(mrun[r], tm);
            float sc = __expf(mrun[r] - mnew);
            float ps = 0.f;
            int row = g * 4 + r;
#pragma unroll
            for (int j = 0; j < 4; j++) {
                float p = __expf(sfr[j][r] - mnew);
                ps += p;
                int key = j * 16 + lr;
                plds[w][row][key ^ ((row & 7) << 3)] = f2bf(p);
            }
#pragma unroll
            for (int mk = 1; mk < 16; mk <<= 1) ps += __shfl_xor(ps, mk, 64);
            mrun[r] = mnew;
            lrun[r] = lrun[r] * sc + ps;
#pragma unroll
            for (int d = 0; d < 4; d++) oacc[d][r] *= sc;
        }
        // read P as A-fragments (row = lr, 8 consecutive keys per lane)
        bf16x8 pa[2];
#pragma unroll
        for (int ks = 0; ks < 2; ks++) {
            int base = (ks * 32 + g * 8) ^ ((lr & 7) << 3);
            u16x8v t = *reinterpret_cast<const u16x8v*>(&plds[w][lr][base]);
            pa[ks] = __builtin_bit_cast(bf16x8, t);
        }
        // O += P * V   (V^T stored [n][h][dh][l])
#pragma unroll
        for (int d = 0; d < 4; d++) {
#pragma unroll
            for (int ks = 0; ks < 2; ks++) {
                const size_t vb = ((size_t)(n * H + hh) * DH + d * 16 + lr) * L
                                  + kt * 64 + ks * 32 + g * 8;
                bf16x8 v8 = ldfrag(Vt + vb);
                oacc[d] = __builtin_amdgcn_mfma_f32_16x16x32_bf16(pa[ks], v8, oacc[d], 0, 0, 0);
            }
        }
    }

    // finalize own source
    float ofin[4][4];
#pragma unroll
    for (int r = 0; r < 4; r++) {
        float inv = __builtin_amdgcn_rcpf(lrun[r]);
#pragma unroll
        for (int d = 0; d < 4; d++) ofin[d][r] = oacc[d][r] * inv;
    }

    // combine the two sources through LDS
    if (s == 0) {
#pragma unroll
        for (int d = 0; d < 4; d++)
#pragma unroll
            for (int r = 0; r < 4; r++) comb[wq][d * 4 + r][lane] = ofin[d][r];
    }
    __syncthreads();
    if (s == 1) {
        float* ob = out + (size_t)oi * ((size_t)NB * L * D);
#pragma unroll
        for (int r = 0; r < 4; r++) {
            int row = l0 + g * 4 + r;
            float mr = maskrow[n * L + row];
#pragma unroll
            for (int d = 0; d < 4; d++) {
                float v = 0.5f * (ofin[d][r] + comb[wq][d * 4 + r][lane]);
                v = (mr > 0.f) ? v : 0.f;
                ob[((size_t)n * L + row) * D + hh * DH + d * 16 + lr] = v;
            }
        }
    }
}

extern "C" void kernel_launch(void* const* d_in, const int* in_sizes, int n_in,
                              void* d_out, int out_size, void* d_ws, size_t ws_size,
                              hipStream_t stream) {
    const float* input1 = (const float*)d_in[0];
    const float* mask1  = (const float*)d_in[1];
    const float* input2 = (const float*)d_in[2];
    const float* mask2  = (const float*)d_in[3];
    const float* Wm[6]  = {(const float*)d_in[4], (const float*)d_in[5], (const float*)d_in[6],
                           (const float*)d_in[7], (const float*)d_in[8], (const float*)d_in[9]};
    u16*   ws  = (u16*)d_ws;
    float* out = (float*)d_out;

    k_split<<<(int)(E / 4 / 256), 256, 0, stream>>>(input1, ws + OFF_X1H, ws + OFF_X1L, (int)(E / 4));
    k_split<<<(int)(E / 4 / 256), 256, 0, stream>>>(input2, ws + OFF_X2H, ws + OFF_X2L, (int)(E / 4));
    for (int i = 0; i < 6; i++)
        k_split<<<(int)(WE / 4 / 256), 256, 0, stream>>>(Wm[i], ws + OFF_WH + (size_t)i * WE,
                                                         ws + OFF_WL + (size_t)i * WE, (int)(WE / 4));
    k_vlen<<<8, 256, 0, stream>>>(mask1, mask2, (int*)(ws + OFF_VLEN));
    k_proj<<<1536, 256, 0, stream>>>(ws);
    k_attn<<<1024, 512, 0, stream>>>(ws, mask1, mask2, out);
}

// Round 3
// 340.490 us; speedup vs baseline: 1.8868x; 1.6246x over previous
//
#include <hip/hip_runtime.h>

#define DEV static __device__ __forceinline__

typedef unsigned short u16;
typedef short bf16x8 __attribute__((ext_vector_type(8)));
typedef u16 u16x8v __attribute__((ext_vector_type(8)));
typedef u16 u16x4v __attribute__((ext_vector_type(4)));
typedef float f32x4 __attribute__((ext_vector_type(4)));

static constexpr int NB = 4, L = 1024, D = 512, H = 8, DH = 64;
static constexpr size_t E  = (size_t)NB * L * D;   // 2,097,152
static constexpr size_t WE = (size_t)D * D;        // 262,144

// d_ws layout in u16 units
static constexpr size_t OFF_X1H = 0;
static constexpr size_t OFF_X1L = OFF_X1H + E;
static constexpr size_t OFF_X2H = OFF_X1L + E;
static constexpr size_t OFF_X2L = OFF_X2H + E;
static constexpr size_t OFF_WH  = OFF_X2L + E;       // 6 x WE
static constexpr size_t OFF_WL  = OFF_WH + 6 * WE;   // 6 x WE
static constexpr size_t OFF_QKV = OFF_WL + 6 * WE;
// OFF_QKV + {0:q1h,1E:q1l,2E:k1h,3E:k1l,4E:q2h,5E:q2l,6E:k2h,7E:k2l,8E:v1t,9E:v2t}
// K buffers are stored dh-SWIZZLED (dh ^= (key&7)<<3); V^T stored key-SWIZZLED
// (key ^= (dh&7)<<3 within each 64-key tile) so that linear global_load_lds
// staging yields bank-conflict-free ds_read_b128 fragments.
static constexpr size_t OFF_VLEN = OFF_QKV + 10 * E; // int[8] (s*4+n)

DEV u16 f2bf(float x) {
    unsigned u = __builtin_bit_cast(unsigned, x);
    unsigned r = u + 0x7FFFu + ((u >> 16) & 1u);
    return (u16)(r >> 16);
}
DEV float bf2f(u16 h) {
    unsigned u = ((unsigned)h) << 16;
    return __builtin_bit_cast(float, u);
}
DEV bf16x8 ldfrag(const u16* p) {
    u16x8v t = *reinterpret_cast<const u16x8v*>(p);
    return __builtin_bit_cast(bf16x8, t);
}
typedef __attribute__((address_space(1))) const unsigned gas_u32;
typedef __attribute__((address_space(3))) unsigned las_u32;
DEV void gld16(const u16* g, u16* l) {
    __builtin_amdgcn_global_load_lds((gas_u32*)g, (las_u32*)l, 16, 0, 0);
}

// ---------------- split fp32 -> (hi, lo) bf16 ----------------
__global__ __launch_bounds__(256) void k_split(const float* __restrict__ in,
                                               u16* __restrict__ hi, u16* __restrict__ lo,
                                               int n4) {
    int i = blockIdx.x * 256 + threadIdx.x;
    if (i >= n4) return;
    float4 v = reinterpret_cast<const float4*>(in)[i];
    float xs[4] = {v.x, v.y, v.z, v.w};
    u16x4v h, l;
#pragma unroll
    for (int j = 0; j < 4; j++) {
        u16 hh = f2bf(xs[j]);
        h[j] = hh;
        l[j] = f2bf(xs[j] - bf2f(hh));
    }
    reinterpret_cast<u16x4v*>(hi)[i] = h;
    reinterpret_cast<u16x4v*>(lo)[i] = l;
}

// ---------------- valid-length per (src, n): prefix-mask sum ----------------
__global__ __launch_bounds__(256) void k_vlen(const float* __restrict__ m1,
                                              const float* __restrict__ m2,
                                              int* __restrict__ vl) {
    int b = blockIdx.x;            // 0..7 : s*4+n
    int s = b >> 2, n = b & 3;
    const float* m = (s ? m2 : m1) + n * L;
    float p = 0.f;
    for (int i = threadIdx.x; i < L; i += 256) p += m[i];
#pragma unroll
    for (int mk = 1; mk < 64; mk <<= 1) p += __shfl_xor(p, mk, 64);
    __shared__ float w4[4];
    if ((threadIdx.x & 63) == 0) w4[threadIdx.x >> 6] = p;
    __syncthreads();
    if (threadIdx.x == 0) vl[b] = (int)(w4[0] + w4[1] + w4[2] + w4[3] + 0.5f);
}

// ---------------- projections, 128x64 block tile, 32 rows/wave ----------------
__global__ __launch_bounds__(256) void k_proj(u16* __restrict__ ws) {
    const int b     = blockIdx.x;
    const int proj  = b >> 8;        // 0..5 : q1,k1,v1,q2,k2,v2
    const int rem   = b & 255;
    const int mtile = rem >> 3;
    const int ntile = rem & 7;
    const int tid   = threadIdx.x;
    const int w     = tid >> 6;
    const int lane  = tid & 63;
    const int lr    = lane & 15;
    const int g     = lane >> 4;

    const int src  = proj / 3;
    const int kind = proj % 3;
    const u16* Xh = ws + (src ? OFF_X2H : OFF_X1H);
    const u16* Xl = ws + (src ? OFF_X2L : OFF_X1L);
    const u16* Wh = ws + OFF_WH + (size_t)proj * WE;
    const u16* Wl = ws + OFF_WL + (size_t)proj * WE;

    const int m0 = mtile * 128 + w * 32;
    const int n0 = ntile * 64;

    f32x4 acc[2][4];
#pragma unroll
    for (int rb = 0; rb < 2; rb++)
#pragma unroll
        for (int cb = 0; cb < 4; cb++) acc[rb][cb] = {0.f, 0.f, 0.f, 0.f};

    const u16* xh0 = Xh + (size_t)(m0 + lr) * D + g * 8;
    const u16* xh1 = Xh + (size_t)(m0 + 16 + lr) * D + g * 8;
    const u16* xl0 = Xl + (size_t)(m0 + lr) * D + g * 8;
    const u16* xl1 = Xl + (size_t)(m0 + 16 + lr) * D + g * 8;
#pragma unroll 4
    for (int e = 0; e < D; e += 32) {
        bf16x8 ah0 = ldfrag(xh0 + e), ah1 = ldfrag(xh1 + e);
        bf16x8 al0 = ldfrag(xl0 + e), al1 = ldfrag(xl1 + e);
#pragma unroll
        for (int cb = 0; cb < 4; cb++) {
            const u16* pwh = Wh + (size_t)(n0 + cb * 16 + lr) * D + e + g * 8;
            const u16* pwl = Wl + (size_t)(n0 + cb * 16 + lr) * D + e + g * 8;
            bf16x8 bh = ldfrag(pwh);
            bf16x8 bl = ldfrag(pwl);
            acc[0][cb] = __builtin_amdgcn_mfma_f32_16x16x32_bf16(ah0, bh, acc[0][cb], 0, 0, 0);
            acc[0][cb] = __builtin_amdgcn_mfma_f32_16x16x32_bf16(ah0, bl, acc[0][cb], 0, 0, 0);
            acc[0][cb] = __builtin_amdgcn_mfma_f32_16x16x32_bf16(al0, bh, acc[0][cb], 0, 0, 0);
            acc[1][cb] = __builtin_amdgcn_mfma_f32_16x16x32_bf16(ah1, bh, acc[1][cb], 0, 0, 0);
            acc[1][cb] = __builtin_amdgcn_mfma_f32_16x16x32_bf16(ah1, bl, acc[1][cb], 0, 0, 0);
            acc[1][cb] = __builtin_amdgcn_mfma_f32_16x16x32_bf16(al1, bh, acc[1][cb], 0, 0, 0);
        }
    }

    if (kind < 2) {
        u16* dhi = ws + OFF_QKV + (size_t)(src * 4 + kind * 2) * E;
        u16* dlo = dhi + E;
#pragma unroll
        for (int rb = 0; rb < 2; rb++)
#pragma unroll
            for (int cb = 0; cb < 4; cb++) {
                int d  = n0 + cb * 16 + lr;
                int hh = d >> 6, dh = d & 63;
#pragma unroll
                for (int r = 0; r < 4; r++) {
                    int m = m0 + rb * 16 + g * 4 + r;
                    int n = m >> 10, li = m & 1023;
                    // K stored dh-swizzled for conflict-free LDS fragment reads
                    int dhs = kind ? (dh ^ ((li & 7) << 3)) : dh;
                    size_t idx = ((size_t)(n * H + hh) * L + li) * DH + dhs;
                    float v = acc[rb][cb][r];
                    u16 hv = f2bf(v);
                    dhi[idx] = hv;
                    dlo[idx] = f2bf(v - bf2f(hv));
                }
            }
    } else {
        u16* vt = ws + OFF_QKV + (size_t)(8 + src) * E;
#pragma unroll
        for (int rb = 0; rb < 2; rb++)
#pragma unroll
            for (int cb = 0; cb < 4; cb++) {
                int d  = n0 + cb * 16 + lr;
                int hh = d >> 6, dh = d & 63;
                int m  = m0 + rb * 16 + g * 4;
                int n  = m >> 10, li = m & 1023;
                int lis = li ^ ((dh & 7) << 3);   // key-swizzle within 64-key tile
                u16x4v pk;
#pragma unroll
                for (int r = 0; r < 4; r++) pk[r] = f2bf(acc[rb][cb][r]);
                *reinterpret_cast<u16x4v*>(vt + ((size_t)(n * H + hh) * DH + dh) * L + lis) = pk;
            }
    }
}

// ---------------- fused two-source flash attention, LDS-staged K/V ----------------
// grid: 2 outputs x 4 n x 8 h x 16 qtiles = 1024 blocks of 512 threads.
// waves 0-3: key-source 0, waves 4-7: key-source 1; combine via LDS.
__global__ __launch_bounds__(512) void k_attn(const u16* __restrict__ ws,
                                              const float* __restrict__ mask1,
                                              const float* __restrict__ mask2,
                                              float* __restrict__ out) {
    __shared__ __align__(16) u16 kbuf[2][2][64][64];  // [src][hi/lo][key][dh-swz] 32KB
    __shared__ __align__(16) u16 vbuf[2][64][64];     // [src][dh][key-swz]        16KB
    __shared__ __align__(16) u16 plds[8][16][64];     // per-wave P, XOR-swizzled  16KB

    const int b    = blockIdx.x;
    const int oi   = b >> 9;
    const int rem  = b & 511;
    const int qt   = rem & 15;
    const int hh   = (rem >> 4) & 7;
    const int n    = rem >> 7;
    const int tid  = threadIdx.x;
    const int w    = tid >> 6;
    const int s    = w >> 2;        // key source
    const int wq   = w & 3;         // q sub-tile
    const int lane = tid & 63;
    const int lr   = lane & 15;
    const int g    = lane >> 4;

    const size_t nh = (size_t)(n * H + hh);
    const u16* Qh = ws + OFF_QKV + (size_t)(oi * 4) * E;
    const u16* Ql = Qh + E;
    const float* maskrow = oi ? mask2 : mask1;
    const float* maskc   = s  ? mask2 : mask1;
    const int* vl = (const int*)(ws + OFF_VLEN);

    const int l0 = qt * 64 + wq * 16;
    const size_t qbase = (nh * L + l0 + lr) * DH + g * 8;
    bf16x8 qh0 = ldfrag(Qh + qbase), qh1 = ldfrag(Qh + qbase + 32);
    bf16x8 ql0 = ldfrag(Ql + qbase), ql1 = ldfrag(Ql + qbase + 32);

    float mrun[4], lrun[4];
    f32x4 oacc[4];
#pragma unroll
    for (int r = 0; r < 4; r++) { mrun[r] = -1e30f; lrun[r] = 0.f; }
#pragma unroll
    for (int d = 0; d < 4; d++) oacc[d] = {0.f, 0.f, 0.f, 0.f};

    const int nkt0 = (vl[n] + 63) >> 6;
    const int nkt1 = (vl[4 + n] + 63) >> 6;
    const int mykt = s ? nkt1 : nkt0;
    const int nktmax = nkt0 > nkt1 ? nkt0 : nkt1;

    // staging: 48 x 1KB chunks per kt, 6 per wave.
    // chunk c: src cs=c/24, r=c%24; r<16 -> K (hi/lo = r>>3), else V.
    const int lane8 = lane >> 3, lanec = lane & 7;

#pragma unroll 1
    for (int kt = 0; kt < nktmax; kt++) {
        __syncthreads();   // previous tile's compute done; safe to overwrite LDS
#pragma unroll
        for (int i = 0; i < 6; i++) {
            const int c  = w * 6 + i;
            const int cs = c / 24, cr = c % 24;
            if (cr < 16) {
                const int hl = cr >> 3, rr = cr & 7;
                const u16* K = ws + OFF_QKV + (size_t)(2 + cs * 4 + hl) * E;
                const u16* src = K + (nh * L + kt * 64 + rr * 8 + lane8) * DH + lanec * 8;
                gld16(src, &kbuf[cs][hl][rr * 8][0]);
            } else {
                const int rr = cr - 16;
                const u16* V = ws + OFF_QKV + (size_t)(8 + cs) * E;
                const u16* src = V + (nh * DH + rr * 8 + lane8) * L + kt * 64 + lanec * 8;
                gld16(src, &vbuf[cs][rr * 8][0]);
            }
        }
        __syncthreads();   // vmcnt drained before barrier -> staged data visible

        if (kt < mykt) {
            f32x4 sfr[4];
#pragma unroll
            for (int j = 0; j < 4; j++) {
                const int row = j * 16 + lr;      // key within tile
                const int t0 = g ^ (row & 7);
                const int t1 = (g + 4) ^ (row & 7);
                bf16x8 kh0 = ldfrag(&kbuf[s][0][row][t0 * 8]);
                bf16x8 kh1 = ldfrag(&kbuf[s][0][row][t1 * 8]);
                bf16x8 kl0 = ldfrag(&kbuf[s][1][row][t0 * 8]);
                bf16x8 kl1 = ldfrag(&kbuf[s][1][row][t1 * 8]);
                f32x4 a = {0.f, 0.f, 0.f, 0.f};
                a = __builtin_amdgcn_mfma_f32_16x16x32_bf16(qh0, kh0, a, 0, 0, 0);
                a = __builtin_amdgcn_mfma_f32_16x16x32_bf16(qh1, kh1, a, 0, 0, 0);
                a = __builtin_amdgcn_mfma_f32_16x16x32_bf16(qh0, kl0, a, 0, 0, 0);
                a = __builtin_amdgcn_mfma_f32_16x16x32_bf16(qh1, kl1, a, 0, 0, 0);
                a = __builtin_amdgcn_mfma_f32_16x16x32_bf16(ql0, kh0, a, 0, 0, 0);
                a = __builtin_amdgcn_mfma_f32_16x16x32_bf16(ql1, kh1, a, 0, 0, 0);
                float sub = (maskc[n * L + kt * 64 + row] > 0.f) ? 0.f : 10000.f;
                a[0] -= sub; a[1] -= sub; a[2] -= sub; a[3] -= sub;
                sfr[j] = a;
            }
            // online softmax per q-row r (replicated across the 16 lr lanes)
#pragma unroll
            for (int r = 0; r < 4; r++) {
                float tm = fmaxf(fmaxf(sfr[0][r], sfr[1][r]), fmaxf(sfr[2][r], sfr[3][r]));
#pragma unroll
                for (int mk = 1; mk < 16; mk <<= 1) tm = fmaxf(tm, __shfl_xor(tm, mk, 64));
                float mnew = fmaxf(mrun[r], tm);
                float sc = __expf(mrun[r] - mnew);
                float ps = 0.f;
                int row = g * 4 + r;
#pragma unroll
                for (int j = 0; j < 4; j++) {
                    float p = __expf(sfr[j][r] - mnew);
                    ps += p;
                    int key = j * 16 + lr;
                    plds[w][row][key ^ ((row & 7) << 3)] = f2bf(p);
                }
#pragma unroll
                for (int mk = 1; mk < 16; mk <<= 1) ps += __shfl_xor(ps, mk, 64);
                mrun[r] = mnew;
                lrun[r] = lrun[r] * sc + ps;
#pragma unroll
                for (int d = 0; d < 4; d++) oacc[d][r] *= sc;
            }
            bf16x8 pa[2];
#pragma unroll
            for (int ks = 0; ks < 2; ks++) {
                int base = (ks * 32 + g * 8) ^ ((lr & 7) << 3);
                u16x8v t = *reinterpret_cast<const u16x8v*>(&plds[w][lr][base]);
                pa[ks] = __builtin_bit_cast(bf16x8, t);
            }
#pragma unroll
            for (int d = 0; d < 4; d++) {
                const int dh = d * 16 + lr;
#pragma unroll
                for (int ks = 0; ks < 2; ks++) {
                    const int t = (ks * 4 + g) ^ (dh & 7);
                    bf16x8 v8 = ldfrag(&vbuf[s][dh][t * 8]);
                    oacc[d] = __builtin_amdgcn_mfma_f32_16x16x32_bf16(pa[ks], v8, oacc[d], 0, 0, 0);
                }
            }
        }
    }

    // finalize own source
    float ofin[4][4];
#pragma unroll
    for (int r = 0; r < 4; r++) {
        float inv = __builtin_amdgcn_rcpf(lrun[r]);
#pragma unroll
        for (int d = 0; d < 4; d++) ofin[d][r] = oacc[d][r] * inv;
    }

    // combine the two sources through LDS (reuse kbuf as f32 comb buffer)
    float (*comb)[16][64] = (float(*)[16][64])&kbuf[0][0][0][0];
    __syncthreads();
    if (s == 0) {
#pragma unroll
        for (int d = 0; d < 4; d++)
#pragma unroll
            for (int r = 0; r < 4; r++) comb[wq][d * 4 + r][lane] = ofin[d][r];
    }
    __syncthreads();
    if (s == 1) {
        float* ob = out + (size_t)oi * ((size_t)NB * L * D);
#pragma unroll
        for (int r = 0; r < 4; r++) {
            int row = l0 + g * 4 + r;
            float mr = maskrow[n * L + row];
#pragma unroll
            for (int d = 0; d < 4; d++) {
                float v = 0.5f * (ofin[d][r] + comb[wq][d * 4 + r][lane]);
                v = (mr > 0.f) ? v : 0.f;
                ob[((size_t)n * L + row) * D + hh * DH + d * 16 + lr] = v;
            }
        }
    }
}

extern "C" void kernel_launch(void* const* d_in, const int* in_sizes, int n_in,
                              void* d_out, int out_size, void* d_ws, size_t ws_size,
                              hipStream_t stream) {
    const float* input1 = (const float*)d_in[0];
    const float* mask1  = (const float*)d_in[1];
    const float* input2 = (const float*)d_in[2];
    const float* mask2  = (const float*)d_in[3];
    const float* Wm[6]  = {(const float*)d_in[4], (const float*)d_in[5], (const float*)d_in[6],
                           (const float*)d_in[7], (const float*)d_in[8], (const float*)d_in[9]};
    u16*   ws  = (u16*)d_ws;
    float* out = (float*)d_out;

    k_split<<<(int)(E / 4 / 256), 256, 0, stream>>>(input1, ws + OFF_X1H, ws + OFF_X1L, (int)(E / 4));
    k_split<<<(int)(E / 4 / 256), 256, 0, stream>>>(input2, ws + OFF_X2H, ws + OFF_X2L, (int)(E / 4));
    for (int i = 0; i < 6; i++)
        k_split<<<(int)(WE / 4 / 256), 256, 0, stream>>>(Wm[i], ws + OFF_WH + (size_t)i * WE,
                                                         ws + OFF_WL + (size_t)i * WE, (int)(WE / 4));
    k_vlen<<<8, 256, 0, stream>>>(mask1, mask2, (int*)(ws + OFF_VLEN));
    k_proj<<<1536, 256, 0, stream>>>(ws);
    k_attn<<<1024, 512, 0, stream>>>(ws, mask1, mask2, out);
}